// Round 10
// baseline (898.363 us; speedup 1.0000x reference)
//
#include <hip/hip_runtime.h>
#include <cmath>

#define EPSF 1e-5f
typedef unsigned int  uint32;
typedef unsigned short u16;
typedef __attribute__((ext_vector_type(8))) short bfrag;   // 8 bf16 = 4 VGPRs
typedef __attribute__((ext_vector_type(4))) float f32x4;

constexpr int Qn   = 16384;
constexpr int KS   = 168;    // fhat K stride (bf16) = 336 B
constexpr int PXS  = 42;     // px stride (u16)
constexpr int AGS  = 168;    // aggs stride
constexpr int Nd   = 4096;
constexpr int GRID = 768;    // persistent: 3 blocks/CU
constexpr float LOG2E = 1.4426950408889634f;

constexpr int OFF_W1  = 0;                 // W_fc1 (xLOG2E) 9x5x512
constexpr int OFF_WM1 = 23040;             // W_mlp1 8x5x512
constexpr int OFF_W2  = 43520;             // W_fc2 (xLOG2E)
constexpr int OFF_WM2 = 66560;             // W_mlp2
constexpr int OFF_WLB = 87040;
constexpr int OFF_WSC = 87552;
constexpr int OFF_WCL = 90112;
constexpr int END_W   = 90624;
constexpr int BN_LB = 0;
constexpr int BN_SC = 20;
constexpr int BN_CL = 168;
constexpr int BN_M1 = 188;
constexpr int BN_M2 = 444;
constexpr int BN_TOT = 700;
constexpr int OFF_FT  = END_W + 2 * BN_TOT;
constexpr int PREP_N  = END_W + BN_TOT;

__device__ __forceinline__ u16 f2b(float f) {
    uint32 u = __float_as_uint(f);
    uint32 r = (u + 0x7fffu + ((u >> 16) & 1u)) >> 16;
    return (u16)r;
}
__device__ __forceinline__ float b2f(u16 h) {
    return __uint_as_float(((uint32)h) << 16);
}
__device__ __forceinline__ uint32 cvtpk(float a, float b) {
    uint32 r;
    asm("v_cvt_pk_bf16_f32 %0, %1, %2" : "=v"(r) : "v"(a), "v"(b));
    return r;
}
__device__ __forceinline__ u16 cvt1(float a) { return (u16)cvtpk(a, a); }
__device__ __forceinline__ float exp2_hw(float x) { return __builtin_amdgcn_exp2f(x); }

// ---------------- prep (unchanged) ----------------
__global__ __launch_bounds__(256) void prep_weights(
    const float* __restrict__ Wfc1, const float* __restrict__ Wmlp1,
    const float* __restrict__ Wfc2, const float* __restrict__ Wmlp2,
    const float* __restrict__ Wlb,  const float* __restrict__ Wsc,
    const float* __restrict__ Wcl,
    const float* __restrict__ g_lb, const float* __restrict__ b_lb,
    const float* __restrict__ m_lb, const float* __restrict__ v_lb,
    const float* __restrict__ g_sc, const float* __restrict__ b_sc,
    const float* __restrict__ m_sc, const float* __restrict__ v_sc,
    const float* __restrict__ g_cl, const float* __restrict__ b_cl,
    const float* __restrict__ m_cl, const float* __restrict__ v_cl,
    const float* __restrict__ g1, const float* __restrict__ b1,
    const float* __restrict__ m1, const float* __restrict__ v1,
    const float* __restrict__ g2, const float* __restrict__ b2,
    const float* __restrict__ m2, const float* __restrict__ v2,
    u16* __restrict__ ws16)
{
    int i = blockIdx.x * 256 + threadIdx.x;
    if (i >= PREP_N) return;
    if (i >= END_W) {
        int j = i - END_W;
        const float *g, *bb, *m, *v; int o2;
        if (j < BN_SC)      { g = g_lb; bb = b_lb; m = m_lb; v = v_lb; o2 = j - BN_LB; }
        else if (j < BN_CL) { g = g_sc; bb = b_sc; m = m_sc; v = v_sc; o2 = j - BN_SC; }
        else if (j < BN_M1) { g = g_cl; bb = b_cl; m = m_cl; v = v_cl; o2 = j - BN_CL; }
        else if (j < BN_M2) { g = g1;   bb = b1;   m = m1;   v = v1;   o2 = j - BN_M1; }
        else                { g = g2;   bb = b2;   m = m2;   v = v2;   o2 = j - BN_M2; }
        int o = o2 >> 1;
        float sc_ = g[o] * rsqrtf(v[o] + EPSF);
        ((float*)(ws16 + END_W))[j] = (o2 & 1) ? (bb[o] - m[o] * sc_) : sc_;
        return;
    }
    int lane = (i >> 3) & 63, jj = i & 7;
    int row16 = lane & 15;
    int kf = ((lane >> 4) << 3) + jj;
    float v = 0.f;
    if (i < OFF_WLB) {
        const float* src; int nrows; int idx; bool fc = false;
        if (i < OFF_WM1)      { src = Wfc1;  nrows = 138; idx = i - OFF_W1;  fc = true; }
        else if (i < OFF_W2)  { src = Wmlp1; nrows = 128; idx = i - OFF_WM1; }
        else if (i < OFF_WM2) { src = Wfc2;  nrows = 138; idx = i - OFF_W2;  fc = true; }
        else                  { src = Wmlp2; nrows = 128; idx = i - OFF_WM2; }
        int t = idx >> 9, nt = t / 5, kt = t - nt * 5;
        int row = nt * 16 + row16;
        int kp  = kt * 32 + kf;
        int k   = (kp < 10) ? kp : kp - 2;
        if (row < nrows && kp < 140 && kp != 10 && kp != 11) {
            v = src[row * 138 + k];
            if (fc) v *= LOG2E;
        }
    } else {
        const float* src; int nrows; int idx;
        if (i < OFF_WSC)      { src = Wlb; nrows = 10; idx = i - OFF_WLB; }
        else if (i < OFF_WCL) { src = Wsc; nrows = 74; idx = i - OFF_WCL >= 0 && i < OFF_WCL ? i - OFF_WSC : i - OFF_WSC; idx = i - OFF_WSC; }
        else                  { src = Wcl; nrows = 10; idx = i - OFF_WCL; }
        int t = idx >> 9;
        int row = t * 16 + row16;
        if (row < nrows && kf < 10) v = src[row * 10 + kf];
    }
    ws16[i] = f2b(v);
}

// ---- helpers ----
__device__ __forceinline__ void mfma32p(const bfrag (&af)[2][5], const bfrag* bf,
                                        f32x4 &a0, f32x4 &a1) {
    const f32x4 zf = {0.f, 0.f, 0.f, 0.f};
    a0 = zf; a1 = zf;
    #pragma unroll
    for (int kt = 0; kt < 5; ++kt) {
        a0 = __builtin_amdgcn_mfma_f32_16x16x32_bf16(af[0][kt], bf[kt], a0, 0, 0, 0);
        a1 = __builtin_amdgcn_mfma_f32_16x16x32_bf16(af[1][kt], bf[kt], a1, 0, 0, 0);
    }
}
__device__ __forceinline__ void mfma16p(const bfrag (&af)[5], const bfrag* bf, f32x4 &a0) {
    const f32x4 zf = {0.f, 0.f, 0.f, 0.f};
    a0 = zf;
    #pragma unroll
    for (int kt = 0; kt < 5; ++kt)
        a0 = __builtin_amdgcn_mfma_f32_16x16x32_bf16(af[kt], bf[kt], a0, 0, 0, 0);
}
template<bool FULL>
__device__ __forceinline__ void soft32(
    const f32x4& a0, const f32x4& a1, int nt, int q,
    int lane, int lrow, int lgr, const u16* fh, u16* aggs)
{
    const int ch  = nt * 16 + lrow;
    const int chp = ch + (ch >= 10 ? 2 : 0);
    if constexpr (FULL) {
        float s = 0.f, num = 0.f;
        #pragma unroll
        for (int r = 0; r < 4; ++r) {
            float e = exp2_hw(a0[r]);
            s += e;
            num += e * b2f(fh[(q * 32 + lgr * 4 + r) * KS + chp]);
        }
        #pragma unroll
        for (int r = 0; r < 4; ++r) {
            float e = exp2_hw(a1[r]);
            s += e;
            num += e * b2f(fh[(q * 32 + 16 + lgr * 4 + r) * KS + chp]);
        }
        s   += __shfl_xor(s, 16);   s   += __shfl_xor(s, 32);
        num += __shfl_xor(num, 16); num += __shfl_xor(num, 32);
        if (lane < 16)
            aggs[q * AGS + chp] = cvt1((ch < 138) ? num * __builtin_amdgcn_rcpf(s) : 0.f);
    } else {
        // ablation stub: keep MFMAs + aggs write live, drop exp/LDS/shfl/rcp
        float s = a0[0] + a0[1] + a0[2] + a0[3] + a1[0] + a1[1] + a1[2] + a1[3];
        if (lane < 16) aggs[q * AGS + chp] = cvt1((ch < 138) ? s * 0.001f : 0.f);
    }
}
__device__ __forceinline__ void soft16f(
    const f32x4& a0, int nt, int q,
    int lane, int lrow, int lgr, const u16* fh, u16* aggs)
{
    const int ch  = nt * 16 + lrow;
    const int chp = ch + (ch >= 10 ? 2 : 0);
    float s = 0.f, num = 0.f;
    #pragma unroll
    for (int r = 0; r < 4; ++r) {
        float e = exp2_hw(a0[r]);
        s += e;
        num += e * b2f(fh[(q * 16 + lgr * 4 + r) * KS + chp]);
    }
    s   += __shfl_xor(s, 16);   s   += __shfl_xor(s, 32);
    num += __shfl_xor(num, 16); num += __shfl_xor(num, 32);
    if (lane < 16)
        aggs[q * AGS + chp] = cvt1((ch < 138) ? num * __builtin_amdgcn_rcpf(s) : 0.f);
}

// ---------------- Stage 1: persistent, 2q/iter, reg-resident B ----------------
template<bool FULL>
__global__ __launch_bounds__(256, 3) void stage1_t(
    const float* __restrict__ feat_lb, const float* __restrict__ feat_sc,
    const int* __restrict__ nm_lb, const int* __restrict__ nm_sc,
    const float* __restrict__ c_lb, const float* __restrict__ c_sc,
    const float* __restrict__ c_q,
    u16* __restrict__ ws16)
{
    __shared__ __align__(16) u16 fhat[64 * KS];      // 21504 B
    __shared__ __align__(16) u16 pxs[2688];          // 5376 B; aggs overlay 16x168
    u16* aggs = pxs;

    const int tid  = threadIdx.x;
    const int lane = tid & 63;
    const int w    = tid >> 6;
    const int lrow = lane & 15;
    const int lgr  = lane >> 4;
    const int q    = w >> 1;
    const int h    = w & 1;

    const u16* W1t  = ws16 + OFF_W1;
    const u16* Wm1t = ws16 + OFF_WM1;
    const float* bn = (const float*)(ws16 + END_W);
    u16* ft = ws16 + OFF_FT;

    // ---- preload att B-fragments for my nt-half (register-resident) ----
    bfrag wb[25];
    #pragma unroll
    for (int u = 0; u < 5; ++u) {
        const int nt = h ? (u < 4 ? 5 + u : 8) : u;
        #pragma unroll
        for (int kt = 0; kt < 5; ++kt)
            wb[u * 5 + kt] = *(const bfrag*)&W1t[((nt * 5 + kt) << 9) + (lane << 3)];
    }
    // ---- conv weights + BN ----
    bfrag wcv[3];
    float2 bnv[3];
    if (h == 0) {
        wcv[0] = *(const bfrag*)&ws16[OFF_WLB + (lane << 3)];
        wcv[1] = *(const bfrag*)&ws16[OFF_WSC + (lane << 3)];
        wcv[2] = *(const bfrag*)&ws16[OFF_WSC + 512 + (lane << 3)];
        bnv[0] = (lrow < 10) ? *(const float2*)&bn[BN_LB + lrow * 2] : float2{0.f, 0.f};
        bnv[1] = *(const float2*)&bn[BN_SC + lrow * 2];
        bnv[2] = *(const float2*)&bn[BN_SC + (16 + lrow) * 2];
    } else {
        #pragma unroll
        for (int t = 0; t < 3; ++t) {
            wcv[t] = *(const bfrag*)&ws16[OFF_WSC + ((2 + t) << 9) + (lane << 3)];
            int o = (2 + t) * 16 + lrow;
            bnv[t] = (o < 74) ? *(const float2*)&bn[BN_SC + o * 2] : float2{0.f, 0.f};
        }
    }

    const f32x4 zf = {0.f, 0.f, 0.f, 0.f};

    for (int bp = blockIdx.x; bp < 16384; bp += GRID) {
        const int bq0 = bp * 2;
        const int b   = bq0 >> 14;
        __syncthreads();   // protect fhat/pxs from previous iteration's readers

        // ---- staging (constant-offset stores) ----
        {
            const float4* flb = (const float4*)(feat_lb + (size_t)bq0 * 2048);
            float4 r0[4];
            #pragma unroll
            for (int it = 0; it < 4; ++it) r0[it] = flb[tid + it * 256];
            const float4* fsc = (const float4*)(feat_sc + (size_t)bq0 * 1024);
            float4 r1[2];
            #pragma unroll
            for (int it = 0; it < 2; ++it) r1[it] = fsc[tid + it * 256];

            u16* d0 = &fhat[(tid >> 5) * KS + 12 + (tid & 31) * 4];
            uint32* d;
            d = (uint32*)(d0);           d[0] = cvtpk(r0[0].x, r0[0].y); d[1] = cvtpk(r0[0].z, r0[0].w);
            d = (uint32*)(d0 + 8 * KS);  d[0] = cvtpk(r0[1].x, r0[1].y); d[1] = cvtpk(r0[1].z, r0[1].w);
            d = (uint32*)(d0 + 32 * KS); d[0] = cvtpk(r0[2].x, r0[2].y); d[1] = cvtpk(r0[2].z, r0[2].w);
            d = (uint32*)(d0 + 40 * KS); d[0] = cvtpk(r0[3].x, r0[3].y); d[1] = cvtpk(r0[3].z, r0[3].w);
            u16* d1 = &fhat[(16 + (tid >> 4)) * KS + 76 + (tid & 15) * 4];
            d = (uint32*)(d1);           d[0] = cvtpk(r1[0].x, r1[0].y); d[1] = cvtpk(r1[0].z, r1[0].w);
            d = (uint32*)(d1 + 32 * KS); d[0] = cvtpk(r1[1].x, r1[1].y); d[1] = cvtpk(r1[1].z, r1[1].w);
        }
        // zero pads: word5 (cols 10,11) rows 0..63; words 70..83 (cols 140..167)
        if (tid < 64) ((uint32*)((char*)fhat + tid * 336))[5] = 0u;
        {
            uint32* zb = (uint32*)((char*)fhat + (tid >> 2) * 336);
            const int w4 = tid & 3;
            zb[70 + w4] = 0u; zb[74 + w4] = 0u; zb[78 + w4] = 0u;
            if (w4 < 2) zb[82 + w4] = 0u;
        }
        if (tid < 64) {
            const int qq = tid >> 5, r = tid & 31;
            const int bq = bq0 + qq;
            const bool lb = r < 16;
            const int idx = lb ? nm_lb[bq * 16 + r] : nm_sc[bq * 16 + (r - 16)];
            const float* nb = lb ? (c_lb + ((size_t)b * Nd + idx) * 3)
                                 : (c_sc + ((size_t)b * Qn + idx) * 3);
            const float qx = c_q[bq * 3 + 0], qy = c_q[bq * 3 + 1], qz = c_q[bq * 3 + 2];
            const float nx = nb[0], ny = nb[1], nz = nb[2];
            const float rx = qx - nx, ry = qy - ny, rz = qz - nz;
            const float dd = sqrtf(rx * rx + ry * ry + rz * rz);
            uint32* pw = (uint32*)&pxs[tid * PXS];
            pw[0] = cvtpk(dd, rx); pw[1] = cvtpk(ry, rz); pw[2] = cvtpk(qx, qy);
            pw[3] = cvtpk(qz, nx); pw[4] = cvtpk(ny, nz);
            #pragma unroll
            for (int z = 5; z < 16; ++z) pw[z] = 0u;
        }
        __syncthreads();

        // ---- convs ----
        {
            bfrag pa1 = *(const bfrag*)&pxs[(q * 32 + 16 + lrow) * PXS + lgr * 8];
            if (h == 0) {
                bfrag pa0 = *(const bfrag*)&pxs[(q * 32 + lrow) * PXS + lgr * 8];
                f32x4 c = __builtin_amdgcn_mfma_f32_16x16x32_bf16(pa0, wcv[0], zf, 0, 0, 0);
                if (lrow < 10) {
                    #pragma unroll
                    for (int r = 0; r < 4; ++r)
                        fhat[(q * 32 + lgr * 4 + r) * KS + lrow] =
                            cvt1(fmaxf(c[r] * bnv[0].x + bnv[0].y, 0.f));
                }
                #pragma unroll
                for (int t = 1; t < 3; ++t) {
                    f32x4 c2 = __builtin_amdgcn_mfma_f32_16x16x32_bf16(pa1, wcv[t], zf, 0, 0, 0);
                    const int o  = (t - 1) * 16 + lrow;
                    const int cp = (o < 10) ? o : o + 2;
                    #pragma unroll
                    for (int r = 0; r < 4; ++r)
                        fhat[(q * 32 + 16 + lgr * 4 + r) * KS + cp] =
                            cvt1(fmaxf(c2[r] * bnv[t].x + bnv[t].y, 0.f));
                }
            } else {
                #pragma unroll
                for (int t = 0; t < 3; ++t) {
                    f32x4 c2 = __builtin_amdgcn_mfma_f32_16x16x32_bf16(pa1, wcv[t], zf, 0, 0, 0);
                    const int o = (2 + t) * 16 + lrow;
                    if (o < 74) {
                        #pragma unroll
                        for (int r = 0; r < 4; ++r)
                            fhat[(q * 32 + 16 + lgr * 4 + r) * KS + o + 2] =
                                cvt1(fmaxf(c2[r] * bnv[t].x + bnv[t].y, 0.f));
                    }
                }
            }
        }
        __syncthreads();

        // ---- att: af from LDS, B register-resident ----
        bfrag af[2][5];
        #pragma unroll
        for (int mt = 0; mt < 2; ++mt)
            #pragma unroll
            for (int kt = 0; kt < 5; ++kt)
                af[mt][kt] = *(const bfrag*)&fhat[(q * 32 + mt * 16 + lrow) * KS + kt * 32 + lgr * 8];

        {
            f32x4 a0, a1;
            if (h == 0) {
                mfma32p(af, wb + 0,  a0, a1); soft32<FULL>(a0, a1, 0, q, lane, lrow, lgr, fhat, aggs);
                mfma32p(af, wb + 5,  a0, a1); soft32<FULL>(a0, a1, 1, q, lane, lrow, lgr, fhat, aggs);
                mfma32p(af, wb + 10, a0, a1); soft32<FULL>(a0, a1, 2, q, lane, lrow, lgr, fhat, aggs);
                mfma32p(af, wb + 15, a0, a1); soft32<FULL>(a0, a1, 3, q, lane, lrow, lgr, fhat, aggs);
                mfma32p(af, wb + 20, a0, a1); soft32<FULL>(a0, a1, 4, q, lane, lrow, lgr, fhat, aggs);
                if (lane < 2)       aggs[q * AGS + 10 + lane] = 0;
                else if (lane < 16) aggs[q * AGS + 144 + lane] = 0;
            } else {
                mfma32p(af, wb + 0,  a0, a1); soft32<FULL>(a0, a1, 5, q, lane, lrow, lgr, fhat, aggs);
                mfma32p(af, wb + 5,  a0, a1); soft32<FULL>(a0, a1, 6, q, lane, lrow, lgr, fhat, aggs);
                mfma32p(af, wb + 10, a0, a1); soft32<FULL>(a0, a1, 7, q, lane, lrow, lgr, fhat, aggs);
                mfma32p(af, wb + 15, a0, a1); soft32<FULL>(a0, a1, 8, q, lane, lrow, lgr, fhat, aggs);
            }
        }
        __syncthreads();

        // ---- MLP 160->128 ----
        bfrag am[5];
        #pragma unroll
        for (int kt = 0; kt < 5; ++kt)
            am[kt] = *(const bfrag*)&aggs[lrow * AGS + kt * 32 + lgr * 8];
        #pragma unroll
        for (int oi = 0; oi < 2; ++oi) {
            const int ot = w * 2 + oi;
            f32x4 c = zf;
            #pragma unroll
            for (int kt = 0; kt < 5; ++kt) {
                bfrag wm = *(const bfrag*)&Wm1t[(((ot * 5) + kt) << 9) + (lane << 3)];
                c = __builtin_amdgcn_mfma_f32_16x16x32_bf16(am[kt], wm, c, 0, 0, 0);
            }
            if (lgr == 0) {
                const int o = ot * 16 + lrow;
                float2 p = *(const float2*)&bn[BN_M1 + o * 2];
                #pragma unroll
                for (int r = 0; r < 2; ++r)
                    ft[(size_t)(bq0 + r) * 128 + o] = cvt1(fmaxf(c[r] * p.x + p.y, 0.f));
            }
        }
    }
}

// ---------------- Stage 2: persistent, 2q/iter, reg-resident B ----------------
__global__ __launch_bounds__(256, 3) void stage2(
    const int* __restrict__ nm_cl, const float* __restrict__ c_q,
    const u16* __restrict__ ws16, float* __restrict__ out)
{
    __shared__ __align__(16) u16 fhat[32 * KS];      // 10752 B
    __shared__ __align__(16) u16 pxs[2688];
    u16* aggs = pxs;

    const int tid  = threadIdx.x;
    const int lane = tid & 63;
    const int w    = tid >> 6;
    const int lrow = lane & 15;
    const int lgr  = lane >> 4;
    const int q    = w >> 1;
    const int h    = w & 1;

    const u16* W2t  = ws16 + OFF_W2;
    const u16* Wm2t = ws16 + OFF_WM2;
    const float* bn = (const float*)(ws16 + END_W);
    const u16* ft   = ws16 + OFF_FT;

    bfrag wb[25];
    #pragma unroll
    for (int u = 0; u < 5; ++u) {
        const int nt = h ? (u < 4 ? 5 + u : 8) : u;
        #pragma unroll
        for (int kt = 0; kt < 5; ++kt)
            wb[u * 5 + kt] = *(const bfrag*)&W2t[((nt * 5 + kt) << 9) + (lane << 3)];
    }
    bfrag wcl = *(const bfrag*)&ws16[OFF_WCL + (lane << 3)];
    float2 bncl = (lrow < 10) ? *(const float2*)&bn[BN_CL + lrow * 2] : float2{0.f, 0.f};

    const f32x4 zf = {0.f, 0.f, 0.f, 0.f};

    for (int bp = blockIdx.x; bp < 16384; bp += GRID) {
        const int bq0 = bp * 2;
        const int b   = bq0 >> 14;
        const int q0  = bq0 & (Qn - 1);
        __syncthreads();

        // zero pads (32 rows)
        if (tid < 32) ((uint32*)((char*)fhat + tid * 336))[5] = 0u;
        {
            uint32* zb = (uint32*)((char*)fhat + (tid >> 3) * 336);
            const int w8 = tid & 7;
            zb[70 + w8] = 0u;
            if (w8 < 6) zb[78 + w8] = 0u;
        }
        if (tid < 32) {
            const int qq = tid >> 4, r = tid & 15;
            const int bq = bq0 + qq;
            const int idx = nm_cl[bq * 16 + r];
            const float* nb = c_q + ((size_t)(b << 14) + idx) * 3;
            const float qx = c_q[bq * 3 + 0], qy = c_q[bq * 3 + 1], qz = c_q[bq * 3 + 2];
            const float nx = nb[0], ny = nb[1], nz = nb[2];
            const float rx = qx - nx, ry = qy - ny, rz = qz - nz;
            const float dd = sqrtf(rx * rx + ry * ry + rz * rz);
            uint32* pw = (uint32*)&pxs[tid * PXS];
            pw[0] = cvtpk(dd, rx); pw[1] = cvtpk(ry, rz); pw[2] = cvtpk(qx, qy);
            pw[3] = cvtpk(qz, nx); pw[4] = cvtpk(ny, nz);
            #pragma unroll
            for (int z = 5; z < 16; ++z) pw[z] = 0u;
        }
        // gather f_tilde rows (32 rows x 64 u32)
        #pragma unroll
        for (int i = 0; i < 8; ++i) {
            int u = tid + i * 256;
            int row = u >> 6, c2 = u & 63;
            int qq = row >> 4;
            int idx = nm_cl[(bq0 + qq) * 16 + (row & 15)];
            const uint32* srow = (const uint32*)(ft + (size_t)((b << 14) + idx) * 128);
            *(uint32*)&fhat[row * KS + 12 + c2 * 2] = srow[c2];
        }
        __syncthreads();

        // conv cl: h==0 wave handles query q
        if (h == 0) {
            bfrag pa = *(const bfrag*)&pxs[(q * 16 + lrow) * PXS + lgr * 8];
            f32x4 c = __builtin_amdgcn_mfma_f32_16x16x32_bf16(pa, wcl, zf, 0, 0, 0);
            if (lrow < 10) {
                #pragma unroll
                for (int r = 0; r < 4; ++r)
                    fhat[(q * 16 + lgr * 4 + r) * KS + lrow] =
                        cvt1(fmaxf(c[r] * bncl.x + bncl.y, 0.f));
            }
        }
        __syncthreads();

        bfrag af[5];
        #pragma unroll
        for (int kt = 0; kt < 5; ++kt)
            af[kt] = *(const bfrag*)&fhat[(q * 16 + lrow) * KS + kt * 32 + lgr * 8];

        {
            f32x4 a0;
            if (h == 0) {
                mfma16p(af, wb + 0,  a0); soft16f(a0, 0, q, lane, lrow, lgr, fhat, aggs);
                mfma16p(af, wb + 5,  a0); soft16f(a0, 1, q, lane, lrow, lgr, fhat, aggs);
                mfma16p(af, wb + 10, a0); soft16f(a0, 2, q, lane, lrow, lgr, fhat, aggs);
                mfma16p(af, wb + 15, a0); soft16f(a0, 3, q, lane, lrow, lgr, fhat, aggs);
                mfma16p(af, wb + 20, a0); soft16f(a0, 4, q, lane, lrow, lgr, fhat, aggs);
                if (lane < 2)       aggs[q * AGS + 10 + lane] = 0;
                else if (lane < 16) aggs[q * AGS + 144 + lane] = 0;
            } else {
                mfma16p(af, wb + 0,  a0); soft16f(a0, 5, q, lane, lrow, lgr, fhat, aggs);
                mfma16p(af, wb + 5,  a0); soft16f(a0, 6, q, lane, lrow, lgr, fhat, aggs);
                mfma16p(af, wb + 10, a0); soft16f(a0, 7, q, lane, lrow, lgr, fhat, aggs);
                mfma16p(af, wb + 15, a0); soft16f(a0, 8, q, lane, lrow, lgr, fhat, aggs);
            }
        }
        __syncthreads();

        // MLP -> out (B,128,Q,1)
        bfrag am[5];
        #pragma unroll
        for (int kt = 0; kt < 5; ++kt)
            am[kt] = *(const bfrag*)&aggs[lrow * AGS + kt * 32 + lgr * 8];
        #pragma unroll
        for (int oi = 0; oi < 2; ++oi) {
            const int ot = w * 2 + oi;
            f32x4 c = zf;
            #pragma unroll
            for (int kt = 0; kt < 5; ++kt) {
                bfrag wm = *(const bfrag*)&Wm2t[(((ot * 5) + kt) << 9) + (lane << 3)];
                c = __builtin_amdgcn_mfma_f32_16x16x32_bf16(am[kt], wm, c, 0, 0, 0);
            }
            if (lgr == 0) {
                const int o = ot * 16 + lrow;
                float2 p = *(const float2*)&bn[BN_M2 + o * 2];
                #pragma unroll
                for (int r = 0; r < 2; ++r)
                    out[((size_t)(b * 128 + o) << 14) + q0 + r] = fmaxf(c[r] * p.x + p.y, 0.f);
            }
        }
    }
}

extern "C" void kernel_launch(void* const* d_in, const int* in_sizes, int n_in,
                              void* d_out, int out_size, void* d_ws, size_t ws_size,
                              hipStream_t stream)
{
    const float* feat_lb = (const float*)d_in[0];
    const float* feat_sc = (const float*)d_in[1];
    const int*   nm_lb   = (const int*)d_in[2];
    const int*   nm_sc   = (const int*)d_in[3];
    const float* c_lb    = (const float*)d_in[4];
    const float* c_sc    = (const float*)d_in[5];
    const float* c_q     = (const float*)d_in[6];
    const int*   nm_cl   = (const int*)d_in[7];
    const float* W_lb = (const float*)d_in[8];
    const float* g_lb = (const float*)d_in[9];
    const float* b_lb = (const float*)d_in[10];
    const float* m_lb = (const float*)d_in[11];
    const float* v_lb = (const float*)d_in[12];
    const float* W_sc = (const float*)d_in[13];
    const float* g_sc = (const float*)d_in[14];
    const float* b_sc = (const float*)d_in[15];
    const float* m_sc = (const float*)d_in[16];
    const float* v_sc = (const float*)d_in[17];
    const float* W_fc1  = (const float*)d_in[18];
    const float* W_mlp1 = (const float*)d_in[19];
    const float* g1 = (const float*)d_in[20];
    const float* b1 = (const float*)d_in[21];
    const float* m1 = (const float*)d_in[22];
    const float* v1 = (const float*)d_in[23];
    const float* W_cl = (const float*)d_in[24];
    const float* g_cl = (const float*)d_in[25];
    const float* b_cl = (const float*)d_in[26];
    const float* m_cl = (const float*)d_in[27];
    const float* v_cl = (const float*)d_in[28];
    const float* W_fc2  = (const float*)d_in[29];
    const float* W_mlp2 = (const float*)d_in[30];
    const float* g2 = (const float*)d_in[31];
    const float* b2 = (const float*)d_in[32];
    const float* m2 = (const float*)d_in[33];
    const float* v2 = (const float*)d_in[34];

    u16* ws16 = (u16*)d_ws;
    float* out = (float*)d_out;

    hipLaunchKernelGGL(prep_weights, dim3((PREP_N + 255) / 256), dim3(256), 0, stream,
        W_fc1, W_mlp1, W_fc2, W_mlp2, W_lb, W_sc, W_cl,
        g_lb, b_lb, m_lb, v_lb, g_sc, b_sc, m_sc, v_sc,
        g_cl, b_cl, m_cl, v_cl, g1, b1, m1, v1, g2, b2, m2, v2, ws16);

    // ablation probe: identical structure, softmax stubbed; ft fully
    // overwritten by the real stage1 below, so output is unaffected.
    hipLaunchKernelGGL((stage1_t<false>), dim3(GRID), dim3(256), 0, stream,
        feat_lb, feat_sc, nm_lb, nm_sc, c_lb, c_sc, c_q, ws16);

    hipLaunchKernelGGL((stage1_t<true>), dim3(GRID), dim3(256), 0, stream,
        feat_lb, feat_sc, nm_lb, nm_sc, c_lb, c_sc, c_q, ws16);

    hipLaunchKernelGGL(stage2, dim3(GRID), dim3(256), 0, stream,
        nm_cl, c_q, ws16, out);
}

// Round 11
// 257.697 us; speedup vs baseline: 3.4861x; 3.4861x over previous
//
#include <hip/hip_runtime.h>
#include <cmath>

#define EPSF 1e-5f
typedef unsigned int  uint32;
typedef unsigned short u16;
typedef __attribute__((ext_vector_type(8))) short bfrag;   // 8 bf16 = 4 VGPRs
typedef __attribute__((ext_vector_type(4))) float f32x4;

constexpr int Qn   = 16384;
constexpr int KS   = 168;    // fhat K stride (bf16) = 336 B (2-way banks)
constexpr int PXS  = 42;     // px stride (u16)
constexpr int AGS  = 168;    // aggs stride
constexpr int Nd   = 4096;
constexpr float LOG2E = 1.4426950408889634f;

constexpr int OFF_W1  = 0;                 // W_fc1 (xLOG2E) 9x5x512
constexpr int OFF_WM1 = 23040;             // W_mlp1 8x5x512
constexpr int OFF_W2  = 43520;             // W_fc2 (xLOG2E)
constexpr int OFF_WM2 = 66560;             // W_mlp2
constexpr int OFF_WLB = 87040;
constexpr int OFF_WSC = 87552;
constexpr int OFF_WCL = 90112;
constexpr int END_W   = 90624;
constexpr int BN_LB = 0;
constexpr int BN_SC = 20;
constexpr int BN_CL = 168;
constexpr int BN_M1 = 188;
constexpr int BN_M2 = 444;
constexpr int BN_TOT = 700;
constexpr int OFF_FT  = END_W + 2 * BN_TOT;
constexpr int PREP_N  = END_W + BN_TOT;

__device__ __forceinline__ u16 f2b(float f) {
    uint32 u = __float_as_uint(f);
    uint32 r = (u + 0x7fffu + ((u >> 16) & 1u)) >> 16;
    return (u16)r;
}
__device__ __forceinline__ float b2f(u16 h) {
    return __uint_as_float(((uint32)h) << 16);
}
__device__ __forceinline__ uint32 cvtpk(float a, float b) {
    uint32 r;
    asm("v_cvt_pk_bf16_f32 %0, %1, %2" : "=v"(r) : "v"(a), "v"(b));
    return r;
}
__device__ __forceinline__ u16 cvt1(float a) { return (u16)cvtpk(a, a); }
__device__ __forceinline__ float exp2_hw(float x) { return __builtin_amdgcn_exp2f(x); }

// ---------------- weight pre-conversion + BN pair precompute ----------------
__global__ __launch_bounds__(256) void prep_weights(
    const float* __restrict__ Wfc1, const float* __restrict__ Wmlp1,
    const float* __restrict__ Wfc2, const float* __restrict__ Wmlp2,
    const float* __restrict__ Wlb,  const float* __restrict__ Wsc,
    const float* __restrict__ Wcl,
    const float* __restrict__ g_lb, const float* __restrict__ b_lb,
    const float* __restrict__ m_lb, const float* __restrict__ v_lb,
    const float* __restrict__ g_sc, const float* __restrict__ b_sc,
    const float* __restrict__ m_sc, const float* __restrict__ v_sc,
    const float* __restrict__ g_cl, const float* __restrict__ b_cl,
    const float* __restrict__ m_cl, const float* __restrict__ v_cl,
    const float* __restrict__ g1, const float* __restrict__ b1,
    const float* __restrict__ m1, const float* __restrict__ v1,
    const float* __restrict__ g2, const float* __restrict__ b2,
    const float* __restrict__ m2, const float* __restrict__ v2,
    u16* __restrict__ ws16)
{
    int i = blockIdx.x * 256 + threadIdx.x;
    if (i >= PREP_N) return;
    if (i >= END_W) {                      // BN pairs
        int j = i - END_W;
        const float *g, *bb, *m, *v; int o2;
        if (j < BN_SC)      { g = g_lb; bb = b_lb; m = m_lb; v = v_lb; o2 = j - BN_LB; }
        else if (j < BN_CL) { g = g_sc; bb = b_sc; m = m_sc; v = v_sc; o2 = j - BN_SC; }
        else if (j < BN_M1) { g = g_cl; bb = b_cl; m = m_cl; v = v_cl; o2 = j - BN_CL; }
        else if (j < BN_M2) { g = g1;   bb = b1;   m = m1;   v = v1;   o2 = j - BN_M1; }
        else                { g = g2;   bb = b2;   m = m2;   v = v2;   o2 = j - BN_M2; }
        int o = o2 >> 1;
        float sc_ = g[o] * rsqrtf(v[o] + EPSF);
        ((float*)(ws16 + END_W))[j] = (o2 & 1) ? (bb[o] - m[o] * sc_) : sc_;
        return;
    }
    int lane = (i >> 3) & 63, jj = i & 7;
    int row16 = lane & 15;
    int kf = ((lane >> 4) << 3) + jj;
    float v = 0.f;
    if (i < OFF_WLB) {                    // att / mlp weights, K remapped
        const float* src; int nrows; int idx; bool fc = false;
        if (i < OFF_WM1)      { src = Wfc1;  nrows = 138; idx = i - OFF_W1;  fc = true; }
        else if (i < OFF_W2)  { src = Wmlp1; nrows = 128; idx = i - OFF_WM1; }
        else if (i < OFF_WM2) { src = Wfc2;  nrows = 138; idx = i - OFF_W2;  fc = true; }
        else                  { src = Wmlp2; nrows = 128; idx = i - OFF_WM2; }
        int t = idx >> 9, nt = t / 5, kt = t - nt * 5;
        int row = nt * 16 + row16;
        int kp  = kt * 32 + kf;
        int k   = (kp < 10) ? kp : kp - 2;
        if (row < nrows && kp < 140 && kp != 10 && kp != 11) {
            v = src[row * 138 + k];
            if (fc) v *= LOG2E;
        }
    } else {                              // conv weights, K = 10 (pad 32)
        const float* src; int nrows; int idx;
        if (i < OFF_WSC)      { src = Wlb; nrows = 10; idx = i - OFF_WLB; }
        else if (i < OFF_WCL) { src = Wsc; nrows = 74; idx = i - OFF_WSC; }
        else                  { src = Wcl; nrows = 10; idx = i - OFF_WCL; }
        int t = idx >> 9;
        int row = t * 16 + row16;
        if (row < nrows && kf < 10) v = src[row * 10 + kf];
    }
    ws16[i] = f2b(v);
}

// ---- helpers ----
__device__ __forceinline__ void loadB(bfrag (&bf)[5], const u16* __restrict__ Wt,
                                      int nt, int lane) {
    #pragma unroll
    for (int kt = 0; kt < 5; ++kt)
        bf[kt] = *(const bfrag*)&Wt[((nt * 5 + kt) << 9) + (lane << 3)];
}
__device__ __forceinline__ void mfma32(const bfrag (&af)[2][5], const bfrag (&bf)[5],
                                       f32x4 &a0, f32x4 &a1) {
    const f32x4 zf = {0.f, 0.f, 0.f, 0.f};
    a0 = zf; a1 = zf;
    #pragma unroll
    for (int kt = 0; kt < 5; ++kt) {
        a0 = __builtin_amdgcn_mfma_f32_16x16x32_bf16(af[0][kt], bf[kt], a0, 0, 0, 0);
        a1 = __builtin_amdgcn_mfma_f32_16x16x32_bf16(af[1][kt], bf[kt], a1, 0, 0, 0);
    }
}
__device__ __forceinline__ void mfma16(const bfrag (&af)[5], const bfrag (&bf)[5],
                                       f32x4 &a0) {
    const f32x4 zf = {0.f, 0.f, 0.f, 0.f};
    a0 = zf;
    #pragma unroll
    for (int kt = 0; kt < 5; ++kt)
        a0 = __builtin_amdgcn_mfma_f32_16x16x32_bf16(af[kt], bf[kt], a0, 0, 0, 0);
}
// softmax over 32 rows; logits pre-scaled by LOG2E, no max-subtract
__device__ __forceinline__ void soft32(
    const f32x4& a0, const f32x4& a1, int nt, int q,
    int lane, int lrow, int lgr, const u16* fh, u16* aggs)
{
    const int ch  = nt * 16 + lrow;
    const int chp = ch + (ch >= 10 ? 2 : 0);
    float s = 0.f, num = 0.f;
    #pragma unroll
    for (int r = 0; r < 4; ++r) {
        float e = exp2_hw(a0[r]);
        s += e;
        num += e * b2f(fh[(q * 32 + lgr * 4 + r) * KS + chp]);
    }
    #pragma unroll
    for (int r = 0; r < 4; ++r) {
        float e = exp2_hw(a1[r]);
        s += e;
        num += e * b2f(fh[(q * 32 + 16 + lgr * 4 + r) * KS + chp]);
    }
    s   += __shfl_xor(s, 16);   s   += __shfl_xor(s, 32);
    num += __shfl_xor(num, 16); num += __shfl_xor(num, 32);
    if (lane < 16)
        aggs[q * AGS + chp] = cvt1((ch < 138) ? num * __builtin_amdgcn_rcpf(s) : 0.f);
}
__device__ __forceinline__ void soft16(
    const f32x4& a0, int nt, int q,
    int lane, int lrow, int lgr, const u16* fh, u16* aggs)
{
    const int ch  = nt * 16 + lrow;
    const int chp = ch + (ch >= 10 ? 2 : 0);
    float s = 0.f, num = 0.f;
    #pragma unroll
    for (int r = 0; r < 4; ++r) {
        float e = exp2_hw(a0[r]);
        s += e;
        num += e * b2f(fh[(q * 16 + lgr * 4 + r) * KS + chp]);
    }
    s   += __shfl_xor(s, 16);   s   += __shfl_xor(s, 32);
    num += __shfl_xor(num, 16); num += __shfl_xor(num, 32);
    if (lane < 16)
        aggs[q * AGS + chp] = cvt1((ch < 138) ? num * __builtin_amdgcn_rcpf(s) : 0.f);
}

// ---------------- Stage 1: 2 queries/block, 4 waves, (query, nt-half) ----------------
__global__ __launch_bounds__(256)
__attribute__((amdgpu_waves_per_eu(4, 4)))
void stage1(
    const float* __restrict__ feat_lb, const float* __restrict__ feat_sc,
    const int* __restrict__ nm_lb, const int* __restrict__ nm_sc,
    const float* __restrict__ c_lb, const float* __restrict__ c_sc,
    const float* __restrict__ c_q,
    u16* __restrict__ ws16)
{
    __shared__ __align__(16) u16 fhat[64 * KS];      // 21504 B
    __shared__ __align__(16) u16 pxs[64 * PXS];      // 5376 B; aggs overlay 16x168
    u16* aggs = pxs;

    const int tid  = threadIdx.x;
    const int bq0  = blockIdx.x * 2;
    const int b    = bq0 >> 14;
    const int lane = tid & 63;
    const int w    = tid >> 6;               // 0..3
    const int lrow = lane & 15;
    const int lgr  = lane >> 4;
    const int q    = w >> 1;                 // my query (0..1)
    const int h    = w & 1;                  // my nt-half

    const u16* W1t  = ws16 + OFF_W1;
    const u16* Wm1t = ws16 + OFF_WM1;
    const float* bn = (const float*)(ws16 + END_W);
    u16* ft = ws16 + OFF_FT;

    // ---- prefetch conv weights + BN for my conv subset ----
    bfrag wcv[3];
    float2 bnv[3];
    if (h == 0) {
        wcv[0] = *(const bfrag*)&ws16[OFF_WLB + (lane << 3)];
        wcv[1] = *(const bfrag*)&ws16[OFF_WSC + (lane << 3)];
        wcv[2] = *(const bfrag*)&ws16[OFF_WSC + 512 + (lane << 3)];
        bnv[0] = (lrow < 10) ? *(const float2*)&bn[BN_LB + lrow * 2] : float2{0.f, 0.f};
        bnv[1] = *(const float2*)&bn[BN_SC + lrow * 2];
        bnv[2] = *(const float2*)&bn[BN_SC + (16 + lrow) * 2];
    } else {
        #pragma unroll
        for (int t = 0; t < 3; ++t) {
            wcv[t] = *(const bfrag*)&ws16[OFF_WSC + ((2 + t) << 9) + (lane << 3)];
            int o = (2 + t) * 16 + lrow;
            bnv[t] = (o < 74) ? *(const float2*)&bn[BN_SC + o * 2] : float2{0.f, 0.f};
        }
    }

    // ---- staging: features -> fhat (bf16), zero pads, px ----
    {
        const float4* flb = (const float4*)(feat_lb + (size_t)bq0 * 2048);
        float4 r0[4];
        #pragma unroll
        for (int it = 0; it < 4; ++it) r0[it] = flb[tid + it * 256];
        const float4* fsc = (const float4*)(feat_sc + (size_t)bq0 * 1024);
        float4 r1[2];
        #pragma unroll
        for (int it = 0; it < 2; ++it) r1[it] = fsc[tid + it * 256];
        #pragma unroll
        for (int it = 0; it < 4; ++it) {
            int u = tid + it * 256;
            int qq = u >> 9, rem = u & 511, r = rem >> 5, c4 = rem & 31;
            uint32* d = (uint32*)&fhat[(qq * 32 + r) * KS + 12 + c4 * 4];
            d[0] = cvtpk(r0[it].x, r0[it].y); d[1] = cvtpk(r0[it].z, r0[it].w);
        }
        #pragma unroll
        for (int it = 0; it < 2; ++it) {
            int u = tid + it * 256;
            int qq = u >> 8, rem = u & 255, r = rem >> 4, c4 = rem & 15;
            uint32* d = (uint32*)&fhat[(qq * 32 + 16 + r) * KS + 76 + c4 * 4];
            d[0] = cvtpk(r1[it].x, r1[it].y); d[1] = cvtpk(r1[it].z, r1[it].w);
        }
        for (int u = tid; u < 64 * 15; u += 256) {    // zero cols 10,11 and 140..167
            int row = u / 15, jj = u - row * 15;
            uint32* base = (uint32*)((char*)fhat + row * 336);
            if (jj == 0) base[5] = 0u; else base[69 + jj] = 0u;
        }
    }
    if (tid < 64) {
        const int qq = tid >> 5, r = tid & 31;
        const int bq = bq0 + qq;
        const bool lb = r < 16;
        const int idx = lb ? nm_lb[bq * 16 + r] : nm_sc[bq * 16 + (r - 16)];
        const float* nb = lb ? (c_lb + ((size_t)b * Nd + idx) * 3)
                             : (c_sc + ((size_t)b * Qn + idx) * 3);
        const float qx = c_q[bq * 3 + 0], qy = c_q[bq * 3 + 1], qz = c_q[bq * 3 + 2];
        const float nx = nb[0], ny = nb[1], nz = nb[2];
        const float rx = qx - nx, ry = qy - ny, rz = qz - nz;
        const float dd = sqrtf(rx * rx + ry * ry + rz * rz);
        uint32* pw = (uint32*)&pxs[tid * PXS];
        pw[0] = cvtpk(dd, rx); pw[1] = cvtpk(ry, rz); pw[2] = cvtpk(qx, qy);
        pw[3] = cvtpk(qz, nx); pw[4] = cvtpk(ny, nz);
        #pragma unroll
        for (int z = 5; z < 16; ++z) pw[z] = 0u;
    }
    __syncthreads();

    const f32x4 zf = {0.f, 0.f, 0.f, 0.f};

    // ---- convs via MFMA: wave (q,h) handles its own query's conv subset ----
    {
        bfrag pa1 = *(const bfrag*)&pxs[(q * 32 + 16 + lrow) * PXS + lgr * 8];
        if (h == 0) {
            bfrag pa0 = *(const bfrag*)&pxs[(q * 32 + lrow) * PXS + lgr * 8];
            f32x4 c = __builtin_amdgcn_mfma_f32_16x16x32_bf16(pa0, wcv[0], zf, 0, 0, 0);
            if (lrow < 10) {
                #pragma unroll
                for (int r = 0; r < 4; ++r)
                    fhat[(q * 32 + lgr * 4 + r) * KS + lrow] =
                        cvt1(fmaxf(c[r] * bnv[0].x + bnv[0].y, 0.f));
            }
            #pragma unroll
            for (int t = 1; t < 3; ++t) {
                f32x4 c2 = __builtin_amdgcn_mfma_f32_16x16x32_bf16(pa1, wcv[t], zf, 0, 0, 0);
                const int o  = (t - 1) * 16 + lrow;       // 0..31
                const int cp = (o < 10) ? o : o + 2;
                #pragma unroll
                for (int r = 0; r < 4; ++r)
                    fhat[(q * 32 + 16 + lgr * 4 + r) * KS + cp] =
                        cvt1(fmaxf(c2[r] * bnv[t].x + bnv[t].y, 0.f));
            }
        } else {
            #pragma unroll
            for (int t = 0; t < 3; ++t) {
                f32x4 c2 = __builtin_amdgcn_mfma_f32_16x16x32_bf16(pa1, wcv[t], zf, 0, 0, 0);
                const int o = (2 + t) * 16 + lrow;        // 32..79
                if (o < 74) {
                    #pragma unroll
                    for (int r = 0; r < 4; ++r)
                        fhat[(q * 32 + 16 + lgr * 4 + r) * KS + o + 2] =
                            cvt1(fmaxf(c2[r] * bnv[t].x + bnv[t].y, 0.f));
                }
            }
        }
    }
    __syncthreads();

    // ---- att: af once in regs; 2-wide unit pipeline (explicit ILP) ----
    bfrag af[2][5];
    #pragma unroll
    for (int mt = 0; mt < 2; ++mt)
        #pragma unroll
        for (int kt = 0; kt < 5; ++kt)
            af[mt][kt] = *(const bfrag*)&fhat[(q * 32 + mt * 16 + lrow) * KS + kt * 32 + lgr * 8];

    bfrag pA[5], pB[5];
    f32x4 x0, x1, y0, y1;
    if (h == 0) {
        loadB(pA, W1t, 0, lane); loadB(pB, W1t, 1, lane);
        mfma32(af, pA, x0, x1); mfma32(af, pB, y0, y1);
        loadB(pA, W1t, 2, lane); loadB(pB, W1t, 3, lane);
        soft32(x0, x1, 0, q, lane, lrow, lgr, fhat, aggs);
        soft32(y0, y1, 1, q, lane, lrow, lgr, fhat, aggs);
        mfma32(af, pA, x0, x1); mfma32(af, pB, y0, y1);
        loadB(pA, W1t, 4, lane);
        soft32(x0, x1, 2, q, lane, lrow, lgr, fhat, aggs);
        soft32(y0, y1, 3, q, lane, lrow, lgr, fhat, aggs);
        mfma32(af, pA, x0, x1);
        soft32(x0, x1, 4, q, lane, lrow, lgr, fhat, aggs);
        if (lane < 2)       aggs[q * AGS + 10 + lane] = 0;
        else if (lane < 16) aggs[q * AGS + 144 + lane] = 0;
    } else {
        loadB(pA, W1t, 5, lane); loadB(pB, W1t, 6, lane);
        mfma32(af, pA, x0, x1); mfma32(af, pB, y0, y1);
        loadB(pA, W1t, 7, lane); loadB(pB, W1t, 8, lane);
        soft32(x0, x1, 5, q, lane, lrow, lgr, fhat, aggs);
        soft32(y0, y1, 6, q, lane, lrow, lgr, fhat, aggs);
        mfma32(af, pA, x0, x1); mfma32(af, pB, y0, y1);
        soft32(x0, x1, 7, q, lane, lrow, lgr, fhat, aggs);
        soft32(y0, y1, 8, q, lane, lrow, lgr, fhat, aggs);
    }
    __syncthreads();

    // ---- MLP 160->128: wave w owns output tiles ot = 2w, 2w+1 ----
    bfrag am[5];
    #pragma unroll
    for (int kt = 0; kt < 5; ++kt)
        am[kt] = *(const bfrag*)&aggs[lrow * AGS + kt * 32 + lgr * 8];
    #pragma unroll
    for (int oi = 0; oi < 2; ++oi) {
        const int ot = w * 2 + oi;
        f32x4 c = zf;
        #pragma unroll
        for (int kt = 0; kt < 5; ++kt) {
            bfrag wm = *(const bfrag*)&Wm1t[(((ot * 5) + kt) << 9) + (lane << 3)];
            c = __builtin_amdgcn_mfma_f32_16x16x32_bf16(am[kt], wm, c, 0, 0, 0);
        }
        if (lgr == 0) {
            const int o = ot * 16 + lrow;
            float2 p = *(const float2*)&bn[BN_M1 + o * 2];
            #pragma unroll
            for (int r = 0; r < 2; ++r)
                ft[(size_t)(bq0 + r) * 128 + o] = cvt1(fmaxf(c[r] * p.x + p.y, 0.f));
        }
    }
}

// ---------------- Stage 2: 4 queries/block, wave w -> query w ----------------
__global__ __launch_bounds__(256)
__attribute__((amdgpu_waves_per_eu(4, 4)))
void stage2(
    const int* __restrict__ nm_cl, const float* __restrict__ c_q,
    const u16* __restrict__ ws16, float* __restrict__ out)
{
    __shared__ __align__(16) u16 fhat[64 * KS];
    __shared__ __align__(16) u16 pxs[64 * PXS];
    u16* aggs = pxs;

    const int tid  = threadIdx.x;
    const int bq0  = blockIdx.x * 4;
    const int b    = bq0 >> 14;
    const int q0   = bq0 & (Qn - 1);
    const int lane = tid & 63;
    const int w    = tid >> 6;               // 0..3 = my query
    const int lrow = lane & 15;
    const int lgr  = lane >> 4;

    const u16* W2t  = ws16 + OFF_W2;
    const u16* Wm2t = ws16 + OFF_WM2;
    const float* bn = (const float*)(ws16 + END_W);
    const u16* ft   = ws16 + OFF_FT;

    // conv cl weight + BN
    bfrag wcl = *(const bfrag*)&ws16[OFF_WCL + (lane << 3)];
    float2 bncl = (lrow < 10) ? *(const float2*)&bn[BN_CL + lrow * 2] : float2{0.f, 0.f};

    for (int u = tid; u < 64 * 15; u += 256) {        // zero cols 10,11 and 140..167
        int row = u / 15, jj = u - row * 15;
        uint32* base = (uint32*)((char*)fhat + row * 336);
        if (jj == 0) base[5] = 0u; else base[69 + jj] = 0u;
    }
    if (tid < 64) {
        const int qq = tid >> 4, r = tid & 15;
        const int bq = bq0 + qq;
        const int idx = nm_cl[bq * 16 + r];
        const float* nb = c_q + ((size_t)(b << 14) + idx) * 3;
        const float qx = c_q[bq * 3 + 0], qy = c_q[bq * 3 + 1], qz = c_q[bq * 3 + 2];
        const float nx = nb[0], ny = nb[1], nz = nb[2];
        const float rx = qx - nx, ry = qy - ny, rz = qz - nz;
        const float dd = sqrtf(rx * rx + ry * ry + rz * rz);
        uint32* pw = (uint32*)&pxs[tid * PXS];
        pw[0] = cvtpk(dd, rx); pw[1] = cvtpk(ry, rz); pw[2] = cvtpk(qx, qy);
        pw[3] = cvtpk(qz, nx); pw[4] = cvtpk(ny, nz);
        #pragma unroll
        for (int z = 5; z < 16; ++z) pw[z] = 0u;
    }
    // gather f_tilde rows -> fhat cols 12..139 (bf16 u32 pairs)
    for (int u = tid; u < 4096; u += 256) {
        int row = u >> 6, c2 = u & 63;
        int qq = row >> 4;
        int idx = nm_cl[(bq0 + qq) * 16 + (row & 15)];
        const uint32* srow = (const uint32*)(ft + (size_t)((b << 14) + idx) * 128);
        *(uint32*)&fhat[row * KS + 12 + c2 * 2] = srow[c2];
    }
    __syncthreads();

    const f32x4 zf = {0.f, 0.f, 0.f, 0.f};

    // ---- conv cl via MFMA: wave w -> query w ----
    {
        bfrag pa = *(const bfrag*)&pxs[(w * 16 + lrow) * PXS + lgr * 8];
        f32x4 c = __builtin_amdgcn_mfma_f32_16x16x32_bf16(pa, wcl, zf, 0, 0, 0);
        if (lrow < 10) {
            #pragma unroll
            for (int r = 0; r < 4; ++r)
                fhat[(w * 16 + lgr * 4 + r) * KS + lrow] =
                    cvt1(fmaxf(c[r] * bncl.x + bncl.y, 0.f));
        }
    }
    __syncthreads();

    // ---- att: af once in regs; 2-wide unit pipeline, 9 units ----
    bfrag af[5];
    #pragma unroll
    for (int kt = 0; kt < 5; ++kt)
        af[kt] = *(const bfrag*)&fhat[(w * 16 + lrow) * KS + kt * 32 + lgr * 8];

    bfrag pA[5], pB[5];
    f32x4 x, y;
    loadB(pA, W2t, 0, lane); loadB(pB, W2t, 1, lane);
    mfma16(af, pA, x); mfma16(af, pB, y);
    loadB(pA, W2t, 2, lane); loadB(pB, W2t, 3, lane);
    soft16(x, 0, w, lane, lrow, lgr, fhat, aggs);
    soft16(y, 1, w, lane, lrow, lgr, fhat, aggs);
    mfma16(af, pA, x); mfma16(af, pB, y);
    loadB(pA, W2t, 4, lane); loadB(pB, W2t, 5, lane);
    soft16(x, 2, w, lane, lrow, lgr, fhat, aggs);
    soft16(y, 3, w, lane, lrow, lgr, fhat, aggs);
    mfma16(af, pA, x); mfma16(af, pB, y);
    loadB(pA, W2t, 6, lane); loadB(pB, W2t, 7, lane);
    soft16(x, 4, w, lane, lrow, lgr, fhat, aggs);
    soft16(y, 5, w, lane, lrow, lgr, fhat, aggs);
    mfma16(af, pA, x); mfma16(af, pB, y);
    loadB(pA, W2t, 8, lane);
    soft16(x, 6, w, lane, lrow, lgr, fhat, aggs);
    soft16(y, 7, w, lane, lrow, lgr, fhat, aggs);
    mfma16(af, pA, x);
    soft16(x, 8, w, lane, lrow, lgr, fhat, aggs);
    if (lane < 2)       aggs[w * AGS + 10 + lane] = 0;
    else if (lane < 16) aggs[w * AGS + 144 + lane] = 0;
    __syncthreads();

    // ---- MLP 160->128 -> out (B,128,Q,1) ----
    bfrag am[5];
    #pragma unroll
    for (int kt = 0; kt < 5; ++kt)
        am[kt] = *(const bfrag*)&aggs[lrow * AGS + kt * 32 + lgr * 8];
    #pragma unroll
    for (int oi = 0; oi < 2; ++oi) {
        const int ot = w * 2 + oi;
        f32x4 c = zf;
        #pragma unroll
        for (int kt = 0; kt < 5; ++kt) {
            bfrag wm = *(const bfrag*)&Wm2t[(((ot * 5) + kt) << 9) + (lane << 3)];
            c = __builtin_amdgcn_mfma_f32_16x16x32_bf16(am[kt], wm, c, 0, 0, 0);
        }
        if (lgr == 0) {
            const int o = ot * 16 + lrow;
            float2 p = *(const float2*)&bn[BN_M2 + o * 2];
            #pragma unroll
            for (int r = 0; r < 4; ++r)
                out[((size_t)(b * 128 + o) << 14) + q0 + r] = fmaxf(c[r] * p.x + p.y, 0.f);
        }
    }
}

extern "C" void kernel_launch(void* const* d_in, const int* in_sizes, int n_in,
                              void* d_out, int out_size, void* d_ws, size_t ws_size,
                              hipStream_t stream)
{
    const float* feat_lb = (const float*)d_in[0];
    const float* feat_sc = (const float*)d_in[1];
    const int*   nm_lb   = (const int*)d_in[2];
    const int*   nm_sc   = (const int*)d_in[3];
    const float* c_lb    = (const float*)d_in[4];
    const float* c_sc    = (const float*)d_in[5];
    const float* c_q     = (const float*)d_in[6];
    const int*   nm_cl   = (const int*)d_in[7];
    const float* W_lb = (const float*)d_in[8];
    const float* g_lb = (const float*)d_in[9];
    const float* b_lb = (const float*)d_in[10];
    const float* m_lb = (const float*)d_in[11];
    const float* v_lb = (const float*)d_in[12];
    const float* W_sc = (const float*)d_in[13];
    const float* g_sc = (const float*)d_in[14];
    const float* b_sc = (const float*)d_in[15];
    const float* m_sc = (const float*)d_in[16];
    const float* v_sc = (const float*)d_in[17];
    const float* W_fc1  = (const float*)d_in[18];
    const float* W_mlp1 = (const float*)d_in[19];
    const float* g1 = (const float*)d_in[20];
    const float* b1 = (const float*)d_in[21];
    const float* m1 = (const float*)d_in[22];
    const float* v1 = (const float*)d_in[23];
    const float* W_cl = (const float*)d_in[24];
    const float* g_cl = (const float*)d_in[25];
    const float* b_cl = (const float*)d_in[26];
    const float* m_cl = (const float*)d_in[27];
    const float* v_cl = (const float*)d_in[28];
    const float* W_fc2  = (const float*)d_in[29];
    const float* W_mlp2 = (const float*)d_in[30];
    const float* g2 = (const float*)d_in[31];
    const float* b2 = (const float*)d_in[32];
    const float* m2 = (const float*)d_in[33];
    const float* v2 = (const float*)d_in[34];

    u16* ws16 = (u16*)d_ws;
    float* out = (float*)d_out;

    hipLaunchKernelGGL(prep_weights, dim3((PREP_N + 255) / 256), dim3(256), 0, stream,
        W_fc1, W_mlp1, W_fc2, W_mlp2, W_lb, W_sc, W_cl,
        g_lb, b_lb, m_lb, v_lb, g_sc, b_sc, m_sc, v_sc,
        g_cl, b_cl, m_cl, v_cl, g1, b1, m1, v1, g2, b2, m2, v2, ws16);

    hipLaunchKernelGGL(stage1, dim3(2 * Qn / 2), dim3(256), 0, stream,
        feat_lb, feat_sc, nm_lb, nm_sc, c_lb, c_sc, c_q, ws16);

    hipLaunchKernelGGL(stage2, dim3(2 * Qn / 4), dim3(256), 0, stream,
        nm_cl, c_q, ws16, out);
}

// Round 12
// 225.270 us; speedup vs baseline: 3.9879x; 1.1439x over previous
//
#include <hip/hip_runtime.h>
#include <cmath>

#define EPSF 1e-5f
typedef unsigned int  uint32;
typedef unsigned short u16;
typedef __attribute__((ext_vector_type(8))) short bfrag;   // 8 bf16 = 4 VGPRs
typedef __attribute__((ext_vector_type(4))) float f32x4;

constexpr int Qn   = 16384;
constexpr int KS   = 168;    // fhat K stride (bf16) = 336 B (2-way banks)
constexpr int PXS  = 42;     // px stride (u16)
constexpr int AGS  = 168;    // aggs stride
constexpr int Nd   = 4096;
constexpr float LOG2E = 1.4426950408889634f;

constexpr int OFF_W1  = 0;                 // W_fc1 (xLOG2E) 9x5x512
constexpr int OFF_WM1 = 23040;             // W_mlp1 8x5x512
constexpr int OFF_W2  = 43520;             // W_fc2 (xLOG2E)
constexpr int OFF_WM2 = 66560;             // W_mlp2
constexpr int OFF_WLB = 87040;
constexpr int OFF_WSC = 87552;
constexpr int OFF_WCL = 90112;
constexpr int END_W   = 90624;
constexpr int BN_LB = 0;
constexpr int BN_SC = 20;
constexpr int BN_CL = 168;
constexpr int BN_M1 = 188;
constexpr int BN_M2 = 444;
constexpr int BN_TOT = 700;
constexpr int OFF_FT  = END_W + 2 * BN_TOT;
constexpr int PREP_N  = END_W + BN_TOT;

__device__ __forceinline__ u16 f2b(float f) {
    uint32 u = __float_as_uint(f);
    uint32 r = (u + 0x7fffu + ((u >> 16) & 1u)) >> 16;
    return (u16)r;
}
__device__ __forceinline__ float b2f(u16 h) {
    return __uint_as_float(((uint32)h) << 16);
}
__device__ __forceinline__ uint32 cvtpk(float a, float b) {
    uint32 r;
    asm("v_cvt_pk_bf16_f32 %0, %1, %2" : "=v"(r) : "v"(a), "v"(b));
    return r;
}
__device__ __forceinline__ u16 cvt1(float a) { return (u16)cvtpk(a, a); }
__device__ __forceinline__ float exp2_hw(float x) { return __builtin_amdgcn_exp2f(x); }

// ---------------- weight pre-conversion + BN pair precompute ----------------
__global__ __launch_bounds__(256) void prep_weights(
    const float* __restrict__ Wfc1, const float* __restrict__ Wmlp1,
    const float* __restrict__ Wfc2, const float* __restrict__ Wmlp2,
    const float* __restrict__ Wlb,  const float* __restrict__ Wsc,
    const float* __restrict__ Wcl,
    const float* __restrict__ g_lb, const float* __restrict__ b_lb,
    const float* __restrict__ m_lb, const float* __restrict__ v_lb,
    const float* __restrict__ g_sc, const float* __restrict__ b_sc,
    const float* __restrict__ m_sc, const float* __restrict__ v_sc,
    const float* __restrict__ g_cl, const float* __restrict__ b_cl,
    const float* __restrict__ m_cl, const float* __restrict__ v_cl,
    const float* __restrict__ g1, const float* __restrict__ b1,
    const float* __restrict__ m1, const float* __restrict__ v1,
    const float* __restrict__ g2, const float* __restrict__ b2,
    const float* __restrict__ m2, const float* __restrict__ v2,
    u16* __restrict__ ws16)
{
    int i = blockIdx.x * 256 + threadIdx.x;
    if (i >= PREP_N) return;
    if (i >= END_W) {                      // BN pairs
        int j = i - END_W;
        const float *g, *bb, *m, *v; int o2;
        if (j < BN_SC)      { g = g_lb; bb = b_lb; m = m_lb; v = v_lb; o2 = j - BN_LB; }
        else if (j < BN_CL) { g = g_sc; bb = b_sc; m = m_sc; v = v_sc; o2 = j - BN_SC; }
        else if (j < BN_M1) { g = g_cl; bb = b_cl; m = m_cl; v = v_cl; o2 = j - BN_CL; }
        else if (j < BN_M2) { g = g1;   bb = b1;   m = m1;   v = v1;   o2 = j - BN_M1; }
        else                { g = g2;   bb = b2;   m = m2;   v = v2;   o2 = j - BN_M2; }
        int o = o2 >> 1;
        float sc_ = g[o] * rsqrtf(v[o] + EPSF);
        ((float*)(ws16 + END_W))[j] = (o2 & 1) ? (bb[o] - m[o] * sc_) : sc_;
        return;
    }
    int lane = (i >> 3) & 63, jj = i & 7;
    int row16 = lane & 15;
    int kf = ((lane >> 4) << 3) + jj;
    float v = 0.f;
    if (i < OFF_WLB) {                    // att / mlp weights, K remapped
        const float* src; int nrows; int idx; bool fc = false;
        if (i < OFF_WM1)      { src = Wfc1;  nrows = 138; idx = i - OFF_W1;  fc = true; }
        else if (i < OFF_W2)  { src = Wmlp1; nrows = 128; idx = i - OFF_WM1; }
        else if (i < OFF_WM2) { src = Wfc2;  nrows = 138; idx = i - OFF_W2;  fc = true; }
        else                  { src = Wmlp2; nrows = 128; idx = i - OFF_WM2; }
        int t = idx >> 9, nt = t / 5, kt = t - nt * 5;
        int row = nt * 16 + row16;
        int kp  = kt * 32 + kf;
        int k   = (kp < 10) ? kp : kp - 2;
        if (row < nrows && kp < 140 && kp != 10 && kp != 11) {
            v = src[row * 138 + k];
            if (fc) v *= LOG2E;
        }
    } else {                              // conv weights, K = 10 (pad 32)
        const float* src; int nrows; int idx;
        if (i < OFF_WSC)      { src = Wlb; nrows = 10; idx = i - OFF_WLB; }
        else if (i < OFF_WCL) { src = Wsc; nrows = 74; idx = i - OFF_WSC; }
        else                  { src = Wcl; nrows = 10; idx = i - OFF_WCL; }
        int t = idx >> 9;
        int row = t * 16 + row16;
        if (row < nrows && kf < 10) v = src[row * 10 + kf];
    }
    ws16[i] = f2b(v);
}

// ---- helpers ----
__device__ __forceinline__ void loadB(bfrag (&bf)[5], const u16* __restrict__ Wt,
                                      int nt, int lane) {
    #pragma unroll
    for (int kt = 0; kt < 5; ++kt)
        bf[kt] = *(const bfrag*)&Wt[((nt * 5 + kt) << 9) + (lane << 3)];
}
__device__ __forceinline__ void mfma32(const bfrag (&af)[2][5], const bfrag (&bf)[5],
                                       f32x4 &a0, f32x4 &a1) {
    const f32x4 zf = {0.f, 0.f, 0.f, 0.f};
    a0 = zf; a1 = zf;
    #pragma unroll
    for (int kt = 0; kt < 5; ++kt) {
        a0 = __builtin_amdgcn_mfma_f32_16x16x32_bf16(af[0][kt], bf[kt], a0, 0, 0, 0);
        a1 = __builtin_amdgcn_mfma_f32_16x16x32_bf16(af[1][kt], bf[kt], a1, 0, 0, 0);
    }
}
__device__ __forceinline__ void mfma16(const bfrag (&af)[5], const bfrag (&bf)[5],
                                       f32x4 &a0) {
    const f32x4 zf = {0.f, 0.f, 0.f, 0.f};
    a0 = zf;
    #pragma unroll
    for (int kt = 0; kt < 5; ++kt)
        a0 = __builtin_amdgcn_mfma_f32_16x16x32_bf16(af[kt], bf[kt], a0, 0, 0, 0);
}
// softmax over 32 rows; fr0/fr1 = hoisted row-base pointers (rows lgr*4.. / 16+lgr*4..)
__device__ __forceinline__ void soft32(
    const f32x4& a0, const f32x4& a1, int nt,
    int lane, int lrow, const u16* __restrict__ fr0, const u16* __restrict__ fr1,
    u16* __restrict__ ag)
{
    const int ch  = nt * 16 + lrow;
    const int chp = ch + (ch >= 10 ? 2 : 0);
    float s = 0.f, num = 0.f;
    #pragma unroll
    for (int r = 0; r < 4; ++r) {
        float e = exp2_hw(a0[r]);
        s += e;
        num += e * b2f(fr0[r * KS + chp]);
    }
    #pragma unroll
    for (int r = 0; r < 4; ++r) {
        float e = exp2_hw(a1[r]);
        s += e;
        num += e * b2f(fr1[r * KS + chp]);
    }
    s   += __shfl_xor(s, 16);   s   += __shfl_xor(s, 32);
    num += __shfl_xor(num, 16); num += __shfl_xor(num, 32);
    if (lane < 16)
        ag[chp] = cvt1((ch < 138) ? num * __builtin_amdgcn_rcpf(s) : 0.f);
}
__device__ __forceinline__ void soft16(
    const f32x4& a0, int nt,
    int lane, int lrow, const u16* __restrict__ fr0, u16* __restrict__ ag)
{
    const int ch  = nt * 16 + lrow;
    const int chp = ch + (ch >= 10 ? 2 : 0);
    float s = 0.f, num = 0.f;
    #pragma unroll
    for (int r = 0; r < 4; ++r) {
        float e = exp2_hw(a0[r]);
        s += e;
        num += e * b2f(fr0[r * KS + chp]);
    }
    s   += __shfl_xor(s, 16);   s   += __shfl_xor(s, 32);
    num += __shfl_xor(num, 16); num += __shfl_xor(num, 32);
    if (lane < 16)
        ag[chp] = cvt1((ch < 138) ? num * __builtin_amdgcn_rcpf(s) : 0.f);
}
#define SB() __builtin_amdgcn_sched_barrier(0)

// ---------------- Stage 1: 2 queries/block, 4 waves, (query, nt-half) ----------------
__global__ __launch_bounds__(256, 4) void stage1(
    const float* __restrict__ feat_lb, const float* __restrict__ feat_sc,
    const int* __restrict__ nm_lb, const int* __restrict__ nm_sc,
    const float* __restrict__ c_lb, const float* __restrict__ c_sc,
    const float* __restrict__ c_q,
    u16* __restrict__ ws16)
{
    __shared__ __align__(16) u16 fhat[64 * KS];      // 21504 B
    __shared__ __align__(16) u16 pxs[64 * PXS];      // 5376 B; aggs overlay 16x168
    u16* aggs = pxs;

    const int tid  = threadIdx.x;
    const int bq0  = blockIdx.x * 2;
    const int b    = bq0 >> 14;
    const int lane = tid & 63;
    const int w    = tid >> 6;               // 0..3
    const int lrow = lane & 15;
    const int lgr  = lane >> 4;
    const int q    = w >> 1;                 // my query (0..1)
    const int h    = w & 1;                  // my nt-half

    const u16* W1t  = ws16 + OFF_W1;
    const u16* Wm1t = ws16 + OFF_WM1;
    const float* bn = (const float*)(ws16 + END_W);
    u16* ft = ws16 + OFF_FT;

    // ---- prefetch conv weights + BN for my conv subset ----
    bfrag wcv[3];
    float2 bnv[3];
    if (h == 0) {
        wcv[0] = *(const bfrag*)&ws16[OFF_WLB + (lane << 3)];
        wcv[1] = *(const bfrag*)&ws16[OFF_WSC + (lane << 3)];
        wcv[2] = *(const bfrag*)&ws16[OFF_WSC + 512 + (lane << 3)];
        bnv[0] = (lrow < 10) ? *(const float2*)&bn[BN_LB + lrow * 2] : float2{0.f, 0.f};
        bnv[1] = *(const float2*)&bn[BN_SC + lrow * 2];
        bnv[2] = *(const float2*)&bn[BN_SC + (16 + lrow) * 2];
    } else {
        #pragma unroll
        for (int t = 0; t < 3; ++t) {
            wcv[t] = *(const bfrag*)&ws16[OFF_WSC + ((2 + t) << 9) + (lane << 3)];
            int o = (2 + t) * 16 + lrow;
            bnv[t] = (o < 74) ? *(const float2*)&bn[BN_SC + o * 2] : float2{0.f, 0.f};
        }
    }

    // ---- staging: features -> fhat (bf16), zero pads, px ----
    {
        const float4* flb = (const float4*)(feat_lb + (size_t)bq0 * 2048);
        float4 r0[4];
        #pragma unroll
        for (int it = 0; it < 4; ++it) r0[it] = flb[tid + it * 256];
        const float4* fsc = (const float4*)(feat_sc + (size_t)bq0 * 1024);
        float4 r1[2];
        #pragma unroll
        for (int it = 0; it < 2; ++it) r1[it] = fsc[tid + it * 256];
        #pragma unroll
        for (int it = 0; it < 4; ++it) {
            int u = tid + it * 256;
            int qq = u >> 9, rem = u & 511, r = rem >> 5, c4 = rem & 31;
            uint32* d = (uint32*)&fhat[(qq * 32 + r) * KS + 12 + c4 * 4];
            d[0] = cvtpk(r0[it].x, r0[it].y); d[1] = cvtpk(r0[it].z, r0[it].w);
        }
        #pragma unroll
        for (int it = 0; it < 2; ++it) {
            int u = tid + it * 256;
            int qq = u >> 8, rem = u & 255, r = rem >> 4, c4 = rem & 15;
            uint32* d = (uint32*)&fhat[(qq * 32 + 16 + r) * KS + 76 + c4 * 4];
            d[0] = cvtpk(r1[it].x, r1[it].y); d[1] = cvtpk(r1[it].z, r1[it].w);
        }
        for (int u = tid; u < 64 * 15; u += 256) {    // zero cols 10,11 and 140..167
            int row = u / 15, jj = u - row * 15;
            uint32* base = (uint32*)((char*)fhat + row * 336);
            if (jj == 0) base[5] = 0u; else base[69 + jj] = 0u;
        }
    }
    if (tid < 64) {
        const int qq = tid >> 5, r = tid & 31;
        const int bq = bq0 + qq;
        const bool lb = r < 16;
        const int idx = lb ? nm_lb[bq * 16 + r] : nm_sc[bq * 16 + (r - 16)];
        const float* nb = lb ? (c_lb + ((size_t)b * Nd + idx) * 3)
                             : (c_sc + ((size_t)b * Qn + idx) * 3);
        const float qx = c_q[bq * 3 + 0], qy = c_q[bq * 3 + 1], qz = c_q[bq * 3 + 2];
        const float nx = nb[0], ny = nb[1], nz = nb[2];
        const float rx = qx - nx, ry = qy - ny, rz = qz - nz;
        const float dd = sqrtf(rx * rx + ry * ry + rz * rz);
        uint32* pw = (uint32*)&pxs[tid * PXS];
        pw[0] = cvtpk(dd, rx); pw[1] = cvtpk(ry, rz); pw[2] = cvtpk(qx, qy);
        pw[3] = cvtpk(qz, nx); pw[4] = cvtpk(ny, nz);
        #pragma unroll
        for (int z = 5; z < 16; ++z) pw[z] = 0u;
    }
    __syncthreads();

    const f32x4 zf = {0.f, 0.f, 0.f, 0.f};

    // ---- convs via MFMA: wave (q,h) handles its own query's conv subset ----
    {
        bfrag pa1 = *(const bfrag*)&pxs[(q * 32 + 16 + lrow) * PXS + lgr * 8];
        if (h == 0) {
            bfrag pa0 = *(const bfrag*)&pxs[(q * 32 + lrow) * PXS + lgr * 8];
            f32x4 c = __builtin_amdgcn_mfma_f32_16x16x32_bf16(pa0, wcv[0], zf, 0, 0, 0);
            if (lrow < 10) {
                #pragma unroll
                for (int r = 0; r < 4; ++r)
                    fhat[(q * 32 + lgr * 4 + r) * KS + lrow] =
                        cvt1(fmaxf(c[r] * bnv[0].x + bnv[0].y, 0.f));
            }
            #pragma unroll
            for (int t = 1; t < 3; ++t) {
                f32x4 c2 = __builtin_amdgcn_mfma_f32_16x16x32_bf16(pa1, wcv[t], zf, 0, 0, 0);
                const int o  = (t - 1) * 16 + lrow;       // 0..31
                const int cp = (o < 10) ? o : o + 2;
                #pragma unroll
                for (int r = 0; r < 4; ++r)
                    fhat[(q * 32 + 16 + lgr * 4 + r) * KS + cp] =
                        cvt1(fmaxf(c2[r] * bnv[t].x + bnv[t].y, 0.f));
            }
        } else {
            #pragma unroll
            for (int t = 0; t < 3; ++t) {
                f32x4 c2 = __builtin_amdgcn_mfma_f32_16x16x32_bf16(pa1, wcv[t], zf, 0, 0, 0);
                const int o = (2 + t) * 16 + lrow;        // 32..79
                if (o < 74) {
                    #pragma unroll
                    for (int r = 0; r < 4; ++r)
                        fhat[(q * 32 + 16 + lgr * 4 + r) * KS + o + 2] =
                            cvt1(fmaxf(c2[r] * bnv[t].x + bnv[t].y, 0.f));
                }
            }
        }
    }
    __syncthreads();

    // ---- att: af once in regs; B software-pipelined through b0/b1 ----
    bfrag af[2][5];
    #pragma unroll
    for (int mt = 0; mt < 2; ++mt)
        #pragma unroll
        for (int kt = 0; kt < 5; ++kt)
            af[mt][kt] = *(const bfrag*)&fhat[(q * 32 + mt * 16 + lrow) * KS + kt * 32 + lgr * 8];

    const u16* fr0 = fhat + (q * 32 + lgr * 4) * KS;
    const u16* fr1 = fr0 + 16 * KS;
    u16* ag = aggs + q * AGS;

    bfrag b0[5], b1[5];
    f32x4 a0, a1;
    if (h == 0) {
        loadB(b0, W1t, 0, lane);
        loadB(b1, W1t, 1, lane); mfma32(af, b0, a0, a1); SB(); soft32(a0, a1, 0, lane, lrow, fr0, fr1, ag);
        loadB(b0, W1t, 2, lane); mfma32(af, b1, a0, a1); SB(); soft32(a0, a1, 1, lane, lrow, fr0, fr1, ag);
        loadB(b1, W1t, 3, lane); mfma32(af, b0, a0, a1); SB(); soft32(a0, a1, 2, lane, lrow, fr0, fr1, ag);
        loadB(b0, W1t, 4, lane); mfma32(af, b1, a0, a1); SB(); soft32(a0, a1, 3, lane, lrow, fr0, fr1, ag);
        mfma32(af, b0, a0, a1); soft32(a0, a1, 4, lane, lrow, fr0, fr1, ag);
        if (lane < 2)       ag[10 + lane] = 0;
        else if (lane < 16) ag[144 + lane] = 0;
    } else {
        loadB(b0, W1t, 5, lane);
        loadB(b1, W1t, 6, lane); mfma32(af, b0, a0, a1); SB(); soft32(a0, a1, 5, lane, lrow, fr0, fr1, ag);
        loadB(b0, W1t, 7, lane); mfma32(af, b1, a0, a1); SB(); soft32(a0, a1, 6, lane, lrow, fr0, fr1, ag);
        loadB(b1, W1t, 8, lane); mfma32(af, b0, a0, a1); SB(); soft32(a0, a1, 7, lane, lrow, fr0, fr1, ag);
        mfma32(af, b1, a0, a1); soft32(a0, a1, 8, lane, lrow, fr0, fr1, ag);
    }
    __syncthreads();

    // ---- MLP 160->128: wave w owns output tiles ot = 2w, 2w+1 ----
    bfrag am[5];
    #pragma unroll
    for (int kt = 0; kt < 5; ++kt)
        am[kt] = *(const bfrag*)&aggs[lrow * AGS + kt * 32 + lgr * 8];
    #pragma unroll
    for (int oi = 0; oi < 2; ++oi) {
        const int ot = w * 2 + oi;
        f32x4 c = zf;
        #pragma unroll
        for (int kt = 0; kt < 5; ++kt) {
            bfrag wm = *(const bfrag*)&Wm1t[(((ot * 5) + kt) << 9) + (lane << 3)];
            c = __builtin_amdgcn_mfma_f32_16x16x32_bf16(am[kt], wm, c, 0, 0, 0);
        }
        if (lgr == 0) {
            const int o = ot * 16 + lrow;
            float2 p = *(const float2*)&bn[BN_M1 + o * 2];
            #pragma unroll
            for (int r = 0; r < 2; ++r)
                ft[(size_t)(bq0 + r) * 128 + o] = cvt1(fmaxf(c[r] * p.x + p.y, 0.f));
        }
    }
}

// ---------------- Stage 2: 8 queries/block, 8 waves, wave w -> query w ----------------
__global__ __launch_bounds__(512, 4) void stage2(
    const int* __restrict__ nm_cl, const float* __restrict__ c_q,
    const u16* __restrict__ ws16, float* __restrict__ out)
{
    __shared__ __align__(16) u16 fhat[128 * KS];     // 43008 B
    __shared__ __align__(16) u16 pxs[128 * PXS];     // 10752 B; aggs overlay 16x168
    u16* aggs = pxs;

    const int tid  = threadIdx.x;
    const int bq0  = blockIdx.x * 8;
    const int b    = bq0 >> 14;
    const int q0   = bq0 & (Qn - 1);
    const int lane = tid & 63;
    const int w    = tid >> 6;               // 0..7 = my query
    const int lrow = lane & 15;
    const int lgr  = lane >> 4;

    const u16* W2t  = ws16 + OFF_W2;
    const u16* Wm2t = ws16 + OFF_WM2;
    const float* bn = (const float*)(ws16 + END_W);
    const u16* ft   = ws16 + OFF_FT;

    // conv cl weight + BN
    bfrag wcl = *(const bfrag*)&ws16[OFF_WCL + (lane << 3)];
    float2 bncl = (lrow < 10) ? *(const float2*)&bn[BN_CL + lrow * 2] : float2{0.f, 0.f};

    for (int u = tid; u < 128 * 15; u += 512) {       // zero cols 10,11 and 140..167
        int row = u / 15, jj = u - row * 15;
        uint32* base = (uint32*)((char*)fhat + row * 336);
        if (jj == 0) base[5] = 0u; else base[69 + jj] = 0u;
    }
    if (tid < 128) {
        const int qq = tid >> 4, r = tid & 15;
        const int bq = bq0 + qq;
        const int idx = nm_cl[bq * 16 + r];
        const float* nb = c_q + ((size_t)(b << 14) + idx) * 3;
        const float qx = c_q[bq * 3 + 0], qy = c_q[bq * 3 + 1], qz = c_q[bq * 3 + 2];
        const float nx = nb[0], ny = nb[1], nz = nb[2];
        const float rx = qx - nx, ry = qy - ny, rz = qz - nz;
        const float dd = sqrtf(rx * rx + ry * ry + rz * rz);
        uint32* pw = (uint32*)&pxs[tid * PXS];
        pw[0] = cvtpk(dd, rx); pw[1] = cvtpk(ry, rz); pw[2] = cvtpk(qx, qy);
        pw[3] = cvtpk(qz, nx); pw[4] = cvtpk(ny, nz);
        #pragma unroll
        for (int z = 5; z < 16; ++z) pw[z] = 0u;
    }
    // gather f_tilde rows -> fhat cols 12..139 (bf16 u32 pairs); 128 rows x 64 u32
    #pragma unroll
    for (int i = 0; i < 16; ++i) {
        int u = tid + i * 512;
        int row = u >> 6, c2 = u & 63;
        int qq = row >> 4;
        int idx = nm_cl[(bq0 + qq) * 16 + (row & 15)];
        const uint32* srow = (const uint32*)(ft + (size_t)((b << 14) + idx) * 128);
        *(uint32*)&fhat[row * KS + 12 + c2 * 2] = srow[c2];
    }
    __syncthreads();

    const f32x4 zf = {0.f, 0.f, 0.f, 0.f};

    // ---- conv cl via MFMA: wave w -> query w ----
    {
        bfrag pa = *(const bfrag*)&pxs[(w * 16 + lrow) * PXS + lgr * 8];
        f32x4 c = __builtin_amdgcn_mfma_f32_16x16x32_bf16(pa, wcl, zf, 0, 0, 0);
        if (lrow < 10) {
            #pragma unroll
            for (int r = 0; r < 4; ++r)
                fhat[(w * 16 + lgr * 4 + r) * KS + lrow] =
                    cvt1(fmaxf(c[r] * bncl.x + bncl.y, 0.f));
        }
    }
    __syncthreads();

    // ---- att: af once in regs; B pipelined; 9 units ----
    bfrag af[5];
    #pragma unroll
    for (int kt = 0; kt < 5; ++kt)
        af[kt] = *(const bfrag*)&fhat[(w * 16 + lrow) * KS + kt * 32 + lgr * 8];

    const u16* fr0 = fhat + (w * 16 + lgr * 4) * KS;
    u16* ag = aggs + w * AGS;

    bfrag b0[5], b1[5];
    f32x4 a0;
    loadB(b0, W2t, 0, lane);
    loadB(b1, W2t, 1, lane); mfma16(af, b0, a0); SB(); soft16(a0, 0, lane, lrow, fr0, ag);
    loadB(b0, W2t, 2, lane); mfma16(af, b1, a0); SB(); soft16(a0, 1, lane, lrow, fr0, ag);
    loadB(b1, W2t, 3, lane); mfma16(af, b0, a0); SB(); soft16(a0, 2, lane, lrow, fr0, ag);
    loadB(b0, W2t, 4, lane); mfma16(af, b1, a0); SB(); soft16(a0, 3, lane, lrow, fr0, ag);
    loadB(b1, W2t, 5, lane); mfma16(af, b0, a0); SB(); soft16(a0, 4, lane, lrow, fr0, ag);
    loadB(b0, W2t, 6, lane); mfma16(af, b1, a0); SB(); soft16(a0, 5, lane, lrow, fr0, ag);
    loadB(b1, W2t, 7, lane); mfma16(af, b0, a0); SB(); soft16(a0, 6, lane, lrow, fr0, ag);
    loadB(b0, W2t, 8, lane); mfma16(af, b1, a0); SB(); soft16(a0, 7, lane, lrow, fr0, ag);
    mfma16(af, b0, a0); soft16(a0, 8, lane, lrow, fr0, ag);
    if (lane < 2)       ag[10 + lane] = 0;
    else if (lane < 16) ag[144 + lane] = 0;
    __syncthreads();

    // ---- MLP 160->128: wave w owns output tile ot = w; M rows = 8 queries ----
    bfrag am[5];
    #pragma unroll
    for (int kt = 0; kt < 5; ++kt)
        am[kt] = *(const bfrag*)&aggs[lrow * AGS + kt * 32 + lgr * 8];
    {
        f32x4 c = zf;
        #pragma unroll
        for (int kt = 0; kt < 5; ++kt) {
            bfrag wm = *(const bfrag*)&Wm2t[(((w * 5) + kt) << 9) + (lane << 3)];
            c = __builtin_amdgcn_mfma_f32_16x16x32_bf16(am[kt], wm, c, 0, 0, 0);
        }
        if (lgr < 2) {                     // rows 0..7 = the 8 valid queries
            const int o = w * 16 + lrow;
            float2 p = *(const float2*)&bn[BN_M2 + o * 2];
            #pragma unroll
            for (int r = 0; r < 4; ++r) {
                const int qloc = lgr * 4 + r;
                out[((size_t)(b * 128 + o) << 14) + q0 + qloc] = fmaxf(c[r] * p.x + p.y, 0.f);
            }
        }
    }
}

extern "C" void kernel_launch(void* const* d_in, const int* in_sizes, int n_in,
                              void* d_out, int out_size, void* d_ws, size_t ws_size,
                              hipStream_t stream)
{
    const float* feat_lb = (const float*)d_in[0];
    const float* feat_sc = (const float*)d_in[1];
    const int*   nm_lb   = (const int*)d_in[2];
    const int*   nm_sc   = (const int*)d_in[3];
    const float* c_lb    = (const float*)d_in[4];
    const float* c_sc    = (const float*)d_in[5];
    const float* c_q     = (const float*)d_in[6];
    const int*   nm_cl   = (const int*)d_in[7];
    const float* W_lb = (const float*)d_in[8];
    const float* g_lb = (const float*)d_in[9];
    const float* b_lb = (const float*)d_in[10];
    const float* m_lb = (const float*)d_in[11];
    const float* v_lb = (const float*)d_in[12];
    const float* W_sc = (const float*)d_in[13];
    const float* g_sc = (const float*)d_in[14];
    const float* b_sc = (const float*)d_in[15];
    const float* m_sc = (const float*)d_in[16];
    const float* v_sc = (const float*)d_in[17];
    const float* W_fc1  = (const float*)d_in[18];
    const float* W_mlp1 = (const float*)d_in[19];
    const float* g1 = (const float*)d_in[20];
    const float* b1 = (const float*)d_in[21];
    const float* m1 = (const float*)d_in[22];
    const float* v1 = (const float*)d_in[23];
    const float* W_cl = (const float*)d_in[24];
    const float* g_cl = (const float*)d_in[25];
    const float* b_cl = (const float*)d_in[26];
    const float* m_cl = (const float*)d_in[27];
    const float* v_cl = (const float*)d_in[28];
    const float* W_fc2  = (const float*)d_in[29];
    const float* W_mlp2 = (const float*)d_in[30];
    const float* g2 = (const float*)d_in[31];
    const float* b2 = (const float*)d_in[32];
    const float* m2 = (const float*)d_in[33];
    const float* v2 = (const float*)d_in[34];

    u16* ws16 = (u16*)d_ws;
    float* out = (float*)d_out;

    hipLaunchKernelGGL(prep_weights, dim3((PREP_N + 255) / 256), dim3(256), 0, stream,
        W_fc1, W_mlp1, W_fc2, W_mlp2, W_lb, W_sc, W_cl,
        g_lb, b_lb, m_lb, v_lb, g_sc, b_sc, m_sc, v_sc,
        g_cl, b_cl, m_cl, v_cl, g1, b1, m1, v1, g2, b2, m2, v2, ws16);

    hipLaunchKernelGGL(stage1, dim3(2 * Qn / 2), dim3(256), 0, stream,
        feat_lb, feat_sc, nm_lb, nm_sc, c_lb, c_sc, c_q, ws16);

    hipLaunchKernelGGL(stage2, dim3(2 * Qn / 8), dim3(512), 0, stream,
        nm_cl, c_q, ws16, out);
}